// Round 3
// baseline (52.369 us; speedup 1.0000x reference)
//
#include <hip/hip_runtime.h>

// Fused 6-layer MLP, v3: 2 rows/thread + explicit load prefetch.
// Block = 256 threads = 4 waves; each thread owns rows rowA and rowA+64
// -> 128 rows/block, grid = 512 blocks.
// Per iter: 2 independent global float4 loads (next i), 12 ds_read_b128
// (W1, shared by both rows' FMAs), 96 FMAs. W1 LDS reads per row halved
// vs v2; >=4 loads in flight per wave with unroll 2.

__device__ __forceinline__ float ftanh(float v) {
    float e = __expf(2.0f * v);
    return 1.0f - 2.0f / (e + 1.0f);
}

__device__ __forceinline__ void tiny_layers_and_store(
        const float (&h1)[12], int row, int sub,
        const float* __restrict__ W2, const float* __restrict__ b2,
        const float* __restrict__ W3, const float* __restrict__ b3,
        const float* __restrict__ W4, const float* __restrict__ b4,
        const float* __restrict__ W5, const float* __restrict__ b5,
        const float* __restrict__ W6, const float* __restrict__ b6,
        float* __restrict__ out)
{
    float h2[10];
#pragma unroll
    for (int m = 0; m < 10; ++m) {
        float s = b2[m];
#pragma unroll
        for (int j = 0; j < 12; ++j) s += h1[j] * W2[j * 10 + m];
        h2[m] = ftanh(s);
    }
    float h3[8];
#pragma unroll
    for (int m = 0; m < 8; ++m) {
        float s = b3[m];
#pragma unroll
        for (int j = 0; j < 10; ++j) s += h2[j] * W3[j * 8 + m];
        h3[m] = ftanh(s);
    }
    float h4[6];
#pragma unroll
    for (int m = 0; m < 6; ++m) {
        float s = b4[m];
#pragma unroll
        for (int j = 0; j < 8; ++j) s += h3[j] * W4[j * 6 + m];
        h4[m] = ftanh(s);
    }
    float h5[4];
#pragma unroll
    for (int m = 0; m < 4; ++m) {
        float s = b5[m];
#pragma unroll
        for (int j = 0; j < 6; ++j) s += h4[j] * W5[j * 4 + m];
        h5[m] = ftanh(s);
    }
    float o[10];
#pragma unroll
    for (int m = 0; m < 10; ++m) {
        float s = b6[m];
#pragma unroll
        for (int j = 0; j < 4; ++j) s += h5[j] * W6[j * 10 + m];
        o[m] = s;   // logits
    }

    const size_t H1 = 655360, H2 = 1441792, H3 = 2097152, H4 = 2621440, H5 = 3014656;
    float2* po  = (float2*)(out +      (size_t)row * 10);
    float4* ph1 = (float4*)(out + H1 + (size_t)row * 12);
    float2* ph2 = (float2*)(out + H2 + (size_t)row * 10);
    float4* ph3 = (float4*)(out + H3 + (size_t)row * 8);
    float2* ph4 = (float2*)(out + H4 + (size_t)row * 6);
    float4* ph5 = (float4*)(out + H5 + (size_t)row * 4);

    if (sub == 0) {
        po[0]  = make_float2(o[0], o[1]);
        po[4]  = make_float2(o[8], o[9]);
        ph2[0] = make_float2(h2[0], h2[1]);
        ph2[4] = make_float2(h2[8], h2[9]);
        ph4[1] = make_float2(h4[2], h4[3]);
    } else if (sub == 1) {
        po[1]  = make_float2(o[2], o[3]);
        ph1[0] = make_float4(h1[0], h1[1], h1[2], h1[3]);
        ph2[1] = make_float2(h2[2], h2[3]);
        ph3[0] = make_float4(h3[0], h3[1], h3[2], h3[3]);
        ph4[2] = make_float2(h4[4], h4[5]);
    } else if (sub == 2) {
        po[2]  = make_float2(o[4], o[5]);
        ph1[1] = make_float4(h1[4], h1[5], h1[6], h1[7]);
        ph2[2] = make_float2(h2[4], h2[5]);
        ph3[1] = make_float4(h3[4], h3[5], h3[6], h3[7]);
        ph5[0] = make_float4(h5[0], h5[1], h5[2], h5[3]);
    } else {
        po[3]  = make_float2(o[6], o[7]);
        ph1[2] = make_float4(h1[8], h1[9], h1[10], h1[11]);
        ph2[3] = make_float2(h2[6], h2[7]);
        ph4[0] = make_float2(h4[0], h4[1]);
    }
}

__global__ __launch_bounds__(256, 2)
void mlp_fused3(const float* __restrict__ x,
                const float* __restrict__ W1, const float* __restrict__ b1,
                const float* __restrict__ W2, const float* __restrict__ b2,
                const float* __restrict__ W3, const float* __restrict__ b3,
                const float* __restrict__ W4, const float* __restrict__ b4,
                const float* __restrict__ W5, const float* __restrict__ b5,
                const float* __restrict__ W6, const float* __restrict__ b6,
                float* __restrict__ out)
{
    __shared__ float4 ldsW1[2352];          // 784*12 floats = 37632 B

    const int tid = threadIdx.x;

    // ---- stage W1 into LDS ----
    const float4* w1v = (const float4*)W1;
    for (int t = tid; t < 2352; t += 256) ldsW1[t] = w1v[t];
    __syncthreads();

    const int lane = tid & 63;
    const int wave = tid >> 6;
    const int r    = lane >> 2;             // row within 16-row wave group
    const int sub  = lane & 3;              // k-quarter within 64B line
    const int rowA = (blockIdx.x << 7) + (wave << 4) + r;
    const int rowB = rowA + 64;

    // ---- layer 1: two rows per thread, 4 lanes per row ----
    float accA[12], accB[12];
#pragma unroll
    for (int j = 0; j < 12; ++j) { accA[j] = 0.f; accB[j] = 0.f; }

    const float4* xrowA = (const float4*)(x + (size_t)rowA * 784);
    const float4* xrowB = (const float4*)(x + (size_t)rowB * 784);

    float4 curA = xrowA[sub];
    float4 curB = xrowB[sub];

#pragma unroll 2
    for (int i = 0; i < 48; ++i) {
        float4 nxtA = xrowA[(i + 1) * 4 + sub];
        float4 nxtB = xrowB[(i + 1) * 4 + sub];
        const float4* wb = &ldsW1[i * 48 + sub * 12];
#pragma unroll
        for (int dk = 0; dk < 4; ++dk) {
            float xa = (dk == 0) ? curA.x : (dk == 1) ? curA.y : (dk == 2) ? curA.z : curA.w;
            float xb = (dk == 0) ? curB.x : (dk == 1) ? curB.y : (dk == 2) ? curB.z : curB.w;
            float4 w0 = wb[dk * 3 + 0];
            float4 w1 = wb[dk * 3 + 1];
            float4 w2 = wb[dk * 3 + 2];
            accA[0] += xa * w0.x;  accA[1] += xa * w0.y;  accA[2]  += xa * w0.z;  accA[3]  += xa * w0.w;
            accA[4] += xa * w1.x;  accA[5] += xa * w1.y;  accA[6]  += xa * w1.z;  accA[7]  += xa * w1.w;
            accA[8] += xa * w2.x;  accA[9] += xa * w2.y;  accA[10] += xa * w2.z;  accA[11] += xa * w2.w;
            accB[0] += xb * w0.x;  accB[1] += xb * w0.y;  accB[2]  += xb * w0.z;  accB[3]  += xb * w0.w;
            accB[4] += xb * w1.x;  accB[5] += xb * w1.y;  accB[6]  += xb * w1.z;  accB[7]  += xb * w1.w;
            accB[8] += xb * w2.x;  accB[9] += xb * w2.y;  accB[10] += xb * w2.z;  accB[11] += xb * w2.w;
        }
        curA = nxtA;
        curB = nxtB;
    }
    {   // peeled final iteration i = 48
        const float4* wb = &ldsW1[48 * 48 + sub * 12];
#pragma unroll
        for (int dk = 0; dk < 4; ++dk) {
            float xa = (dk == 0) ? curA.x : (dk == 1) ? curA.y : (dk == 2) ? curA.z : curA.w;
            float xb = (dk == 0) ? curB.x : (dk == 1) ? curB.y : (dk == 2) ? curB.z : curB.w;
            float4 w0 = wb[dk * 3 + 0];
            float4 w1 = wb[dk * 3 + 1];
            float4 w2 = wb[dk * 3 + 2];
            accA[0] += xa * w0.x;  accA[1] += xa * w0.y;  accA[2]  += xa * w0.z;  accA[3]  += xa * w0.w;
            accA[4] += xa * w1.x;  accA[5] += xa * w1.y;  accA[6]  += xa * w1.z;  accA[7]  += xa * w1.w;
            accA[8] += xa * w2.x;  accA[9] += xa * w2.y;  accA[10] += xa * w2.z;  accA[11] += xa * w2.w;
            accB[0] += xb * w0.x;  accB[1] += xb * w0.y;  accB[2]  += xb * w0.z;  accB[3]  += xb * w0.w;
            accB[4] += xb * w1.x;  accB[5] += xb * w1.y;  accB[6]  += xb * w1.z;  accB[7]  += xb * w1.w;
            accB[8] += xb * w2.x;  accB[9] += xb * w2.y;  accB[10] += xb * w2.z;  accB[11] += xb * w2.w;
        }
    }

    // ---- reduce 4 sub-partials + bias + tanh ----
    float h1A[12], h1B[12];
#pragma unroll
    for (int j = 0; j < 12; ++j) {
        float za = accA[j];
        za += __shfl_xor(za, 1);
        za += __shfl_xor(za, 2);
        h1A[j] = ftanh(za + b1[j]);
        float zb = accB[j];
        zb += __shfl_xor(zb, 1);
        zb += __shfl_xor(zb, 2);
        h1B[j] = ftanh(zb + b1[j]);
    }

    // ---- tiny layers + stores, both rows ----
    tiny_layers_and_store(h1A, rowA, sub, W2, b2, W3, b3, W4, b4, W5, b5, W6, b6, out);
    tiny_layers_and_store(h1B, rowB, sub, W2, b2, W3, b3, W4, b4, W5, b5, W6, b6, out);
}

extern "C" void kernel_launch(void* const* d_in, const int* in_sizes, int n_in,
                              void* d_out, int out_size, void* d_ws, size_t ws_size,
                              hipStream_t stream) {
    (void)in_sizes; (void)n_in; (void)d_ws; (void)ws_size; (void)out_size;
    mlp_fused3<<<512, 256, 0, stream>>>(
        (const float*)d_in[0],
        (const float*)d_in[1],  (const float*)d_in[2],
        (const float*)d_in[3],  (const float*)d_in[4],
        (const float*)d_in[5],  (const float*)d_in[6],
        (const float*)d_in[7],  (const float*)d_in[8],
        (const float*)d_in[9],  (const float*)d_in[10],
        (const float*)d_in[11], (const float*)d_in[12],
        (float*)d_out);
}